// Round 21
// baseline (874.371 us; speedup 1.0000x reference)
//
#include <hip/hip_runtime.h>
#include <hip/hip_bf16.h>

// ---------- types ----------
typedef __attribute__((ext_vector_type(8))) unsigned short u16x8;
typedef __attribute__((ext_vector_type(4))) unsigned short u16x4;
typedef __attribute__((ext_vector_type(2))) unsigned int   u32x2;
typedef __attribute__((ext_vector_type(4))) int            i32x4;
typedef __attribute__((ext_vector_type(8))) __bf16         bf16x8;
typedef __attribute__((ext_vector_type(4))) float          f32x4;
typedef __attribute__((address_space(3))) unsigned short   lds_us;

#define SS 1024
#define BB 8
#define DD 1024
#define HH 16
#define HDD 64
#define FF 4096
#define MM 8192   // S*B rows

// async global->LDS, 16B per lane; LDS dest is wave-uniform base + lane*16
#define GL16(g, l) __builtin_amdgcn_global_load_lds( \
    (__attribute__((address_space(1))) const void*)(g), \
    (__attribute__((address_space(3))) void*)(l), 16, 0, 0)

// LDS transpose read: lane gets 4 bf16 at elem-stride 16 from its own addr (+byte imm)
#define TRV(d, a, o) asm volatile("ds_read_b64_tr_b16 %0, %1 offset:" o : "=v"(d) : "v"(a))
// K=16 bf16 MFMA, C/D in VGPRs (gfx950 unified file)
#define MFMA16(acc, pa, vb) asm volatile("v_mfma_f32_16x16x16_bf16 %0, %1, %2, %0" \
    : "+v"(acc) : "v"(pa), "v"(vb))

__device__ __forceinline__ float bf2f(unsigned short u) {
    return __uint_as_float(((unsigned int)u) << 16);
}
__device__ __forceinline__ unsigned short f2bf(float f) {
    return __builtin_bit_cast(unsigned short, (__bf16)f);   // HW RNE cvt
}
__device__ __forceinline__ float quantv(float w, float som, float qm) {
    if (qm == 0.f) {  // 1-bit: sign(w)*mean|w|
        float sgn = (w > 0.f) ? 1.f : ((w < 0.f) ? -1.f : 0.f);
        return sgn * som;
    }
    if (som == 0.f) return 0.f;
    float q = rintf(w / som);
    q = fminf(fmaxf(q, -qm - 1.f), qm);
    return q * som;
}

// ---------- stats: per-tensor max|.|, sum|.| (4-deep pipeline, 128 blocks/tensor) ----------
// 128 blocks/tensor (2176 total, G11 cap) -> fewer concurrent DRAM streams,
// longer contiguous per-block chunks.
__global__ __launch_bounds__(256) void k_stats(const float* __restrict__ w_in, const float* __restrict__ w_out,
                                               const float* __restrict__ w1, const float* __restrict__ w2,
                                               const float* __restrict__ src,
                                               float* __restrict__ pmax, float* __restrict__ psum) {
    const int t = blockIdx.y, blk = blockIdx.x, tid = threadIdx.x;
    const float* base; int n;
    if (t < 4)       { base = w_in  + (size_t)t * 3145728;     n = 3145728; }
    else if (t < 8)  { base = w_out + (size_t)(t-4) * 1048576; n = 1048576; }
    else if (t < 12) { base = w1    + (size_t)(t-8) * 4194304; n = 4194304; }
    else if (t < 16) { base = w2    + (size_t)(t-12) * 4194304; n = 4194304; }
    else             { base = src;                             n = 8388608; }
    const int per = (n >> 2) >> 7;   // float4s per block (128 blocks); multiple of 2048
    const float4* bptr = reinterpret_cast<const float4*>(base) + (size_t)blk * per;
    float mx0 = 0.f, mx1 = 0.f, mx2 = 0.f, mx3 = 0.f;
    float sm0 = 0.f, sm1 = 0.f, sm2 = 0.f, sm3 = 0.f;
    for (int i = tid; i < per; i += 1024) {   // 4 independent loads in flight
        float4 a = bptr[i];
        float4 b4 = bptr[i + 256];
        float4 c = bptr[i + 512];
        float4 d = bptr[i + 768];
        float a0 = fabsf(a.x), a1 = fabsf(a.y), a2 = fabsf(a.z), a3 = fabsf(a.w);
        float b0 = fabsf(b4.x), b1 = fabsf(b4.y), b2 = fabsf(b4.z), b3 = fabsf(b4.w);
        float c0 = fabsf(c.x), c1 = fabsf(c.y), c2 = fabsf(c.z), c3 = fabsf(c.w);
        float d0 = fabsf(d.x), d1 = fabsf(d.y), d2 = fabsf(d.z), d3 = fabsf(d.w);
        mx0 = fmaxf(mx0, fmaxf(fmaxf(a0, a1), fmaxf(a2, a3)));
        mx1 = fmaxf(mx1, fmaxf(fmaxf(b0, b1), fmaxf(b2, b3)));
        mx2 = fmaxf(mx2, fmaxf(fmaxf(c0, c1), fmaxf(c2, c3)));
        mx3 = fmaxf(mx3, fmaxf(fmaxf(d0, d1), fmaxf(d2, d3)));
        sm0 += (a0 + a1) + (a2 + a3);
        sm1 += (b0 + b1) + (b2 + b3);
        sm2 += (c0 + c1) + (c2 + c3);
        sm3 += (d0 + d1) + (d2 + d3);
    }
    float vmax = fmaxf(fmaxf(mx0, mx1), fmaxf(mx2, mx3));
    float vsum = (sm0 + sm1) + (sm2 + sm3);
#pragma unroll
    for (int m = 1; m < 64; m <<= 1) { vmax = fmaxf(vmax, __shfl_xor(vmax, m, 64)); vsum += __shfl_xor(vsum, m, 64); }
    __shared__ float sm[4], su[4];
    const int wave = tid >> 6, lane = tid & 63;
    if (lane == 0) { sm[wave] = vmax; su[wave] = vsum; }
    __syncthreads();
    if (tid == 0) {
        pmax[t * 128 + blk] = fmaxf(fmaxf(sm[0], sm[1]), fmaxf(sm[2], sm[3]));
        psum[t * 128 + blk] = (su[0] + su[1]) + (su[2] + su[3]);
    }
}

// ---------- params: final reduce (128 partials, zero-padded) + softmax(alpha) ----------
__global__ __launch_bounds__(256) void k_params(const float* __restrict__ pmax, const float* __restrict__ psum,
                                                const float* __restrict__ alpha, float* __restrict__ P) {
    __shared__ float rm[256], rs[256];
    const int tid = threadIdx.x;
    for (int t = 0; t < 17; ++t) {
        rm[tid] = (tid < 128) ? pmax[t * 128 + tid] : 0.f;
        rs[tid] = (tid < 128) ? psum[t * 128 + tid] : 0.f;
        __syncthreads();
        for (int s = 128; s > 0; s >>= 1) {
            if (tid < s) { rm[tid] = fmaxf(rm[tid], rm[tid + s]); rs[tid] += rs[tid + s]; }
            __syncthreads();
        }
        if (tid == 0) {
            if (t == 16) {
                P[50] = rm[0] * (1.f / 127.f);
            } else {
                const int nbits[4] = {1, 2, 4, 8};
                const int nb = nbits[t & 3];
                float nsize = (t < 4) ? 3145728.f : ((t < 8) ? 1048576.f : 4194304.f);
                if (nb == 1) { P[16 + 2*t] = rs[0] / nsize; P[17 + 2*t] = 0.f; }
                else { float qm = (float)((1 << (nb - 1)) - 1); P[16 + 2*t] = rm[0] / qm; P[17 + 2*t] = qm; }
            }
        }
        __syncthreads();
    }
    if (tid < 3) {
        float a[4], mx = -1e30f;
#pragma unroll
        for (int i = 0; i < 4; ++i) { a[i] = alpha[tid * 4 + i]; mx = fmaxf(mx, a[i]); }
        float e[4], ssum = 0.f;
#pragma unroll
        for (int i = 0; i < 4; ++i) { e[i] = expf(a[i] - mx); ssum += e[i]; }
#pragma unroll
        for (int i = 0; i < 4; ++i) P[tid * 4 + i] = e[i] / ssum;
    }
}

// ---------- one-block max reduce: out = max(part[0..n)) ----------
__global__ __launch_bounds__(256) void k_rmax(const float* __restrict__ part, int n, float* __restrict__ out) {
    const int tid = threadIdx.x;
    float m = 0.f;
    for (int i = tid; i < n; i += 256) m = fmaxf(m, part[i]);
#pragma unroll
    for (int s = 1; s < 64; s <<= 1) m = fmaxf(m, __shfl_xor(m, s, 64));
    __shared__ float sm[4];
    const int wave = tid >> 6, lane = tid & 63;
    if (lane == 0) sm[wave] = m;
    __syncthreads();
    if (tid == 0) *out = fmaxf(fmaxf(sm[0], sm[1]), fmaxf(sm[2], sm[3]));
}

// ---------- quantize in-proj weights -> i8 (integer part is EXACT per reference) ----------
__global__ __launch_bounds__(256) void k_quant8(const float* __restrict__ w, signed char* __restrict__ out,
                                                const float* __restrict__ P, int per_tensor, int tbase, int ntot) {
    int i = blockIdx.x * 256 + threadIdx.x;
    if (i >= ntot) return;
    int t = tbase + i / per_tensor;
    float som = P[16 + 2*t], qm = P[17 + 2*t];
    float v;
    float x = w[i];
    if (qm == 0.f)      v = (x > 0.f) ? 1.f : ((x < 0.f) ? -1.f : 0.f);
    else if (som == 0.f) v = 0.f;
    else                v = fminf(fmaxf(rintf(x / som), -qm - 1.f), qm);
    out[i] = (signed char)(int)v;
}

// ---------- quantize src -> i8 with per-tensor scale P[50] ----------
__global__ __launch_bounds__(256) void k_si8(const float* __restrict__ in, signed char* __restrict__ out,
                                             const float* __restrict__ P, int n4) {
    int i = blockIdx.x * 256 + threadIdx.x;
    if (i >= n4) return;
    const float sa = P[50];
    const float inv = (sa > 0.f) ? 1.f / sa : 0.f;
    float4 v = reinterpret_cast<const float4*>(in)[i];
    char4 o;
    o.x = (signed char)(int)fminf(fmaxf(rintf(v.x * inv), -127.f), 127.f);
    o.y = (signed char)(int)fminf(fmaxf(rintf(v.y * inv), -127.f), 127.f);
    o.z = (signed char)(int)fminf(fmaxf(rintf(v.z * inv), -127.f), 127.f);
    o.w = (signed char)(int)fminf(fmaxf(rintf(v.w * inv), -127.f), 127.f);
    reinterpret_cast<char4*>(out)[i] = o;
}

// ---------- mixed weights -> per-row i8 + row scale ----------
template <int NE, int MODE>
__global__ __launch_bounds__(256) void k_mixq8(const float* __restrict__ w, signed char* __restrict__ out,
                                               float* __restrict__ sB, const float* __restrict__ P,
                                               int tbase, int prow, size_t sz) {
    const int row = blockIdx.x, tid = threadIdx.x;
    const int L = NE * 256;
    float v[NE];
    float lm = 0.f;
#pragma unroll
    for (int j = 0; j < NE; ++j) {
        int k = j * 256 + tid;
        float acc;
        if (MODE == 0) {
            acc = 0.f;
#pragma unroll
            for (int br = 0; br < 4; ++br) {
                int t = tbase + br;
                acc += P[prow * 4 + br] * quantv(w[(size_t)br * sz + (size_t)row * L + k], P[16 + 2*t], P[17 + 2*t]);
            }
        } else {
            int i = k >> 10, e = k & 1023;
            int t = tbase + i;
            acc = P[i] * quantv(w[(size_t)i * sz + (size_t)row * 1024 + e], P[16 + 2*t], P[17 + 2*t]);
        }
        v[j] = acc;
        lm = fmaxf(lm, fabsf(acc));
    }
#pragma unroll
    for (int m = 1; m < 64; m <<= 1) lm = fmaxf(lm, __shfl_xor(lm, m, 64));
    __shared__ float sm[4];
    const int wave = tid >> 6, lane = tid & 63;
    if (lane == 0) sm[wave] = lm;
    __syncthreads();
    lm = fmaxf(fmaxf(sm[0], sm[1]), fmaxf(sm[2], sm[3]));
    if (tid == 0) sB[row] = lm * (1.f / 127.f);
    const float inv = (lm > 0.f) ? 127.f / lm : 0.f;
#pragma unroll
    for (int j = 0; j < NE; ++j)
        out[(size_t)row * L + j * 256 + tid] =
            (signed char)(int)fminf(fmaxf(rintf(v[j] * inv), -127.f), 127.f);
}

__global__ __launch_bounds__(256) void k_mixb(const float* __restrict__ b, float* __restrict__ out,
                                              const float* __restrict__ P, int prow, int n) {
    int i = blockIdx.x * 256 + threadIdx.x;
    if (i >= n) return;
    float acc = 0.f;
#pragma unroll
    for (int br = 0; br < 4; ++br) acc += P[prow * 4 + br] * b[(size_t)br * n + i];
    out[i] = acc;
}

// ---------- bf16 buffer -> i8 with scale = *amax/127 ----------
__global__ __launch_bounds__(256) void k_q8(const unsigned short* __restrict__ in, signed char* __restrict__ out,
                                            const float* __restrict__ amax, int n8) {
    int i = blockIdx.x * 256 + threadIdx.x;
    if (i >= n8) return;
    const float am = *amax;
    const float inv = (am > 0.f) ? 127.f / am : 0.f;
    u16x8 v = reinterpret_cast<const u16x8*>(in)[i];
    union { signed char c[8]; unsigned long long u; } r;
#pragma unroll
    for (int e = 0; e < 8; ++e) {
        float f = bf2f(v[e]) * inv;
        r.c[e] = (signed char)(int)fminf(fmaxf(rintf(f), -127.f), 127.f);
    }
    reinterpret_cast<unsigned long long*>(out)[i] = r.u;
}

// ---------- i8 GEMM, per-tensor scale pair (qkv; proven in R9) ----------
__global__ __launch_bounds__(256) void k_gemm_i8(const signed char* __restrict__ A,
                                                 const signed char* __restrict__ Bw,
                                                 unsigned short* __restrict__ C,
                                                 const float* __restrict__ bias,
                                                 const float* __restrict__ P, int tIdx,
                                                 int M, int N, int K, int XM, int XN) {
    const int gx = gridDim.x, gy = gridDim.y;
    const int flat = blockIdx.x + gx * blockIdx.y;
    const int xcd = flat & 7, r = flat >> 3;
    const int nloc = gx / XN, mloc = gy / XM;
    const int cm = xcd / XN, cn = xcd - cm * XN;
    const int by = cm * mloc + r / nloc;
    const int bx = cn * nloc + (r - (r / nloc) * nloc);

    __shared__ signed char As[2][128 * 128];
    __shared__ signed char Bs[2][128 * 128];
    const int tid = threadIdx.x;
    const int m0 = by * 128, n0 = bx * 128;
    const int lane = tid & 63, wave = tid >> 6;
    const int wr = wave >> 1, wc = wave & 1;
    const int lr = lane & 15, lg = lane >> 4;
    const int rsub = lane >> 3;
    const int csub = ((lane & 7) ^ rsub) * 16;
    const size_t aoff = (size_t)(m0 + rsub) * K + csub;
    const size_t boff = (size_t)(n0 + rsub) * K + csub;

    i32x4 acc[4][4];
#pragma unroll
    for (int m = 0; m < 4; ++m)
#pragma unroll
        for (int n = 0; n < 4; ++n) acc[m][n] = (i32x4){0, 0, 0, 0};

    auto stage = [&](int buf, int k0) {
#pragma unroll
        for (int it = 0; it < 4; ++it) {
            const int g = it * 4 + wave;
            GL16(A + aoff + (size_t)g * 8 * K + k0, &As[buf][g * 1024]);
            GL16(Bw + boff + (size_t)g * 8 * K + k0, &Bs[buf][g * 1024]);
        }
    };
    auto compute = [&](int buf) {
#pragma unroll
        for (int kh = 0; kh < 2; ++kh) {
            i32x4 af[4], bfr[4];
#pragma unroll
            for (int m = 0; m < 4; ++m) {
                int row = wr * 64 + m * 16 + lr;
                int cidx = (kh * 4 + lg) ^ (lr & 7);
                af[m] = *reinterpret_cast<const i32x4*>(&As[buf][row * 128 + cidx * 16]);
            }
#pragma unroll
            for (int n = 0; n < 4; ++n) {
                int row = wc * 64 + n * 16 + lr;
                int cidx = (kh * 4 + lg) ^ (lr & 7);
                bfr[n] = *reinterpret_cast<const i32x4*>(&Bs[buf][row * 128 + cidx * 16]);
            }
#pragma unroll
            for (int m = 0; m < 4; ++m)
#pragma unroll
                for (int n = 0; n < 4; ++n)
                    acc[m][n] = __builtin_amdgcn_mfma_i32_16x16x64_i8(
                        af[m], bfr[n], acc[m][n], 0, 0, 0);
        }
    };

    stage(0, 0);
    __syncthreads();
    int cur = 0;
    for (int k0 = 128; k0 < K; k0 += 128) {
        stage(cur ^ 1, k0);
        compute(cur);
        __syncthreads();
        cur ^= 1;
    }
    compute(cur);

    const float sab = P[50] * P[16 + 2 * tIdx];
#pragma unroll
    for (int n = 0; n < 4; ++n) {
        const int col = n0 + wc * 64 + n * 16 + lr;
        const float bv = bias[col];
#pragma unroll
        for (int m = 0; m < 4; ++m) {
#pragma unroll
            for (int j = 0; j < 4; ++j) {
                const int row = m0 + wr * 64 + m * 16 + lg * 4 + j;
                float v = (float)acc[m][n][j] * sab + bv;
                C[(size_t)row * N + col] = f2bf(v);
            }
        }
    }
}

// ---------- i8 GEMM with per-column B scale + scalar A scale; GELU; per-block out-max ----------
__device__ __forceinline__ void store_out(float* C, size_t idx, float v) { C[idx] = v; }
__device__ __forceinline__ void store_out(unsigned short* C, size_t idx, float v) { C[idx] = f2bf(v); }

template <typename OutT, bool GELU>
__global__ __launch_bounds__(256) void k_gemm_i8s(const signed char* __restrict__ A,
                                                  const signed char* __restrict__ Bw,
                                                  OutT* __restrict__ C,
                                                  const float* __restrict__ bias,
                                                  const float* __restrict__ sB,
                                                  const float* __restrict__ aAm,
                                                  float* __restrict__ oPart,
                                                  int M, int N, int K, int XM, int XN) {
    const int gx = gridDim.x, gy = gridDim.y;
    const int flat = blockIdx.x + gx * blockIdx.y;
    const int xcd = flat & 7, r = flat >> 3;
    const int nloc = gx / XN, mloc = gy / XM;
    const int cm = xcd / XN, cn = xcd - cm * XN;
    const int by = cm * mloc + r / nloc;
    const int bx = cn * nloc + (r - (r / nloc) * nloc);

    __shared__ signed char As[2][128 * 128];
    __shared__ signed char Bs[2][128 * 128];
    __shared__ float smx[4];
    const int tid = threadIdx.x;
    const int m0 = by * 128, n0 = bx * 128;
    const int lane = tid & 63, wave = tid >> 6;
    const int wr = wave >> 1, wc = wave & 1;
    const int lr = lane & 15, lg = lane >> 4;
    const int rsub = lane >> 3;
    const int csub = ((lane & 7) ^ rsub) * 16;
    const size_t aoff = (size_t)(m0 + rsub) * K + csub;
    const size_t boff = (size_t)(n0 + rsub) * K + csub;

    i32x4 acc[4][4];
#pragma unroll
    for (int m = 0; m < 4; ++m)
#pragma unroll
        for (int n = 0; n < 4; ++n) acc[m][n] = (i32x4){0, 0, 0, 0};

    auto stage = [&](int buf, int k0) {
#pragma unroll
        for (int it = 0; it < 4; ++it) {
            const int g = it * 4 + wave;
            GL16(A + aoff + (size_t)g * 8 * K + k0, &As[buf][g * 1024]);
            GL16(Bw + boff + (size_t)g * 8 * K + k0, &Bs[buf][g * 1024]);
        }
    };
    auto compute = [&](int buf) {
#pragma unroll
        for (int kh = 0; kh < 2; ++kh) {
            i32x4 af[4], bfr[4];
#pragma unroll
            for (int m = 0; m < 4; ++m) {
                int row = wr * 64 + m * 16 + lr;
                int cidx = (kh * 4 + lg) ^ (lr & 7);
                af[m] = *reinterpret_cast<const i32x4*>(&As[buf][row * 128 + cidx * 16]);
            }
#pragma unroll
            for (int n = 0; n < 4; ++n) {
                int row = wc * 64 + n * 16 + lr;
                int cidx = (kh * 4 + lg) ^ (lr & 7);
                bfr[n] = *reinterpret_cast<const i32x4*>(&Bs[buf][row * 128 + cidx * 16]);
            }
#pragma unroll
            for (int m = 0; m < 4; ++m)
#pragma unroll
                for (int n = 0; n < 4; ++n)
                    acc[m][n] = __builtin_amdgcn_mfma_i32_16x16x64_i8(
                        af[m], bfr[n], acc[m][n], 0, 0, 0);
        }
    };

    stage(0, 0);
    __syncthreads();
    int cur = 0;
    for (int k0 = 128; k0 < K; k0 += 128) {
        stage(cur ^ 1, k0);
        compute(cur);
        __syncthreads();
        cur ^= 1;
    }
    compute(cur);

    const float sA = (*aAm) * (1.f / 127.f);
    float lm = 0.f;
#pragma unroll
    for (int n = 0; n < 4; ++n) {
        const int col = n0 + wc * 64 + n * 16 + lr;
        const float sc = sA * sB[col];
        const float bv = bias ? bias[col] : 0.f;
#pragma unroll
        for (int m = 0; m < 4; ++m) {
#pragma unroll
            for (int j = 0; j < 4; ++j) {
                const int row = m0 + wr * 64 + m * 16 + lg * 4 + j;
                float v = (float)acc[m][n][j] * sc + bv;
                if (GELU) v = 0.5f * v * (1.f + erff(v * 0.70710678118654752f));
                store_out(C, (size_t)row * N + col, v);
                if (oPart) lm = fmaxf(lm, fabsf(v));
            }
        }
    }
    if (oPart) {
#pragma unroll
        for (int m = 1; m < 64; m <<= 1) lm = fmaxf(lm, __shfl_xor(lm, m, 64));
        if (lane == 0) smx[wave] = lm;
        __syncthreads();
        if (tid == 0) oPart[flat] = fmaxf(fmaxf(smx[0], smx[1]), fmaxf(smx[2], smx[3]));
    }
}

// ---------- MFMA flash attention: zero-shuffle PV, phase-split q2 streams (R19-proven) ----------
__global__ __launch_bounds__(256) void k_fmfma(const unsigned short* __restrict__ qkvb, int qstride,
                                               unsigned short* __restrict__ outb, int ostride,
                                               float* __restrict__ oPart) {
    __shared__ unsigned short Ks[2][4096];
    __shared__ unsigned short Vs[2][4096];
    __shared__ float smx[4];
    const int tid = threadIdx.x;
    const int lane = tid & 63, wave = tid >> 6;
    const int lr = lane & 15, lg = lane >> 4;
    // grid 1024 = 8 xcd x 16 bh x 8 qidx: all 8 q-blocks of one bh on one XCD
    const int f = blockIdx.x;
    const int bh = (f & 7) * 16 + ((f >> 3) & 15);
    const int s0 = (f >> 7) * 128;
    const int b = bh >> 4, hh = bh & 15;
    const int hb = hh * 64;

    // Q fragments: 2 per wave (rows s0 + wave*32 + q2*16 + lr)
    u16x8 qf[2][2];
#pragma unroll
    for (int q2 = 0; q2 < 2; ++q2) {
        const size_t qb = (size_t)((s0 + wave * 32 + q2 * 16 + lr) * 8 + b) * qstride + hb;
#pragma unroll
        for (int ks = 0; ks < 2; ++ks)
            qf[q2][ks] = *reinterpret_cast<const u16x8*>(qkvb + qb + ks * 32 + lg * 8);
    }
    // staging sources (per-thread, kt-independent parts)
    size_t kOff[2], vOff[2];
#pragma unroll
    for (int it = 0; it < 2; ++it) {
        const int g = it * 256 + tid;
        const int krow = g >> 3, kchs = g & 7;
        kOff[it] = (size_t)(krow * 8 + b) * qstride + 1024 + hb + ((kchs ^ (krow & 7)) * 8);
        const int dblk = (g >> 7) & 3, khi = (g >> 5) & 3, kmid = (g >> 3) & 3, klo = (g >> 1) & 3, dh = g & 1;
        const int vkey = khi * 16 + kmid * 4 + klo;
        vOff[it] = (size_t)(vkey * 8 + b) * qstride + 2048 + hb + dblk * 16 + dh * 8;
    }
    // TRV addresses as AS3 pointers (true 32-bit LDS offsets)
    const lds_us* va0 = (lds_us*)&Vs[0][lg * 64 + lr];
    const lds_us* va1 = (lds_us*)&Vs[1][lg * 64 + lr];

    float m_old[2] = {-1e30f, -1e30f};
    float l_lane[2] = {0.f, 0.f};
    f32x4 oacc[2][4];
#pragma unroll
    for (int q2 = 0; q2 < 2; ++q2)
#pragma unroll
        for (int n = 0; n < 4; ++n) oacc[q2][n] = (f32x4){0.f, 0.f, 0.f, 0.f};

    auto stage = [&](int buf, int kt) {
        const size_t ktoff = (size_t)kt * 512 * qstride;
#pragma unroll
        for (int it = 0; it < 2; ++it) {
            GL16(qkvb + kOff[it] + ktoff, &Ks[buf][it * 2048 + wave * 512]);
            GL16(qkvb + vOff[it] + ktoff, &Vs[buf][it * 2048 + wave * 512]);
        }
    };

    stage(0, 0);
    __syncthreads();
    int cur = 0;
    for (int kt = 0; kt < 16; ++kt) {
        if (kt < 15) stage(cur ^ 1, kt + 1);   // prefetch; drained by barrier below
        // V tr-read fragments: vb[n][dblk], byte imm = dblk*2048+n*512
        const lds_us* va = cur ? va1 : va0;
        u32x2 vb[4][4];
        TRV(vb[0][0], va, "0");    TRV(vb[0][1], va, "2048"); TRV(vb[0][2], va, "4096"); TRV(vb[0][3], va, "6144");
        TRV(vb[1][0], va, "512");  TRV(vb[1][1], va, "2560"); TRV(vb[1][2], va, "4608"); TRV(vb[1][3], va, "6656");
        TRV(vb[2][0], va, "1024"); TRV(vb[2][1], va, "3072"); TRV(vb[2][2], va, "5120"); TRV(vb[2][3], va, "7168");
        TRV(vb[3][0], va, "1536"); TRV(vb[3][1], va, "3584"); TRV(vb[3][2], va, "5632"); TRV(vb[3][3], va, "7680");
        asm volatile("s_waitcnt lgkmcnt(0)" ::: "memory");
        __builtin_amdgcn_sched_barrier(0);
        // ---- phase 1: QK^T for BOTH q2, sharing each Ks ds_read ----
        f32x4 sacc[2][4];
#pragma unroll
        for (int q2 = 0; q2 < 2; ++q2)
#pragma unroll
            for (int n = 0; n < 4; ++n) sacc[q2][n] = (f32x4){0.f, 0.f, 0.f, 0.f};
        __builtin_amdgcn_s_setprio(1);
#pragma unroll
        for (int ks = 0; ks < 2; ++ks) {
#pragma unroll
            for (int n = 0; n < 4; ++n) {
                int row = n * 16 + lr;
                int cidx = (ks * 4 + lg) ^ (lr & 7);
                u16x8 kf = *reinterpret_cast<const u16x8*>(&Ks[cur][row * 64 + cidx * 8]);
                sacc[0][n] = __builtin_amdgcn_mfma_f32_16x16x32_bf16(
                    __builtin_bit_cast(bf16x8, kf), __builtin_bit_cast(bf16x8, qf[0][ks]),
                    sacc[0][n], 0, 0, 0);
                sacc[1][n] = __builtin_amdgcn_mfma_f32_16x16x32_bf16(
                    __builtin_bit_cast(bf16x8, kf), __builtin_bit_cast(bf16x8, qf[1][ks]),
                    sacc[1][n], 0, 0, 0);
            }
        }
        __builtin_amdgcn_s_setprio(0);
        // ---- phase 2: softmax both q2 (independent chains), pack into pa ----
        u32x2 pa[2][4];
        float corr2[2];
#pragma unroll
        for (int q2 = 0; q2 < 2; ++q2) {
            float pmax = -1e30f;
#pragma unroll
            for (int n = 0; n < 4; ++n)
#pragma unroll
                for (int j = 0; j < 4; ++j) { sacc[q2][n][j] *= 0.125f; pmax = fmaxf(pmax, sacc[q2][n][j]); }
            pmax = fmaxf(pmax, __shfl_xor(pmax, 16, 64));
            pmax = fmaxf(pmax, __shfl_xor(pmax, 32, 64));
            const float m_new = fmaxf(m_old[q2], pmax);
            const float corr = __expf(m_old[q2] - m_new);
            float psum = 0.f;
#pragma unroll
            for (int n = 0; n < 4; ++n) {
                float e0 = __expf(sacc[q2][n][0] - m_new);
                float e1 = __expf(sacc[q2][n][1] - m_new);
                float e2 = __expf(sacc[q2][n][2] - m_new);
                float e3 = __expf(sacc[q2][n][3] - m_new);
                psum += (e0 + e1) + (e2 + e3);
                pa[q2][n][0] = (unsigned)f2bf(e0) | ((unsigned)f2bf(e1) << 16);
                pa[q2][n][1] = (unsigned)f2bf(e2) | ((unsigned)f2bf(e3) << 16);
            }
            l_lane[q2] = l_lane[q2] * corr + psum;
            m_old[q2] = m_new;
            corr2[q2] = corr;
        }
        // ---- phase 3: rescale O rows both q2 ----
#pragma unroll
        for (int j = 0; j < 4; ++j) {
            float cj0 = __shfl(corr2[0], lg * 4 + j, 64);
            float cj1 = __shfl(corr2[1], lg * 4 + j, 64);
#pragma unroll
            for (int n = 0; n < 4; ++n) { oacc[0][n][j] *= cj0; oacc[1][n][j] *= cj1; }
        }
        // ---- phase 4: PV interleaved across q2 (two independent MFMA chains) ----
        __builtin_amdgcn_s_setprio(1);
#pragma unroll
        for (int n = 0; n < 4; ++n)
#pragma unroll
            for (int dblk = 0; dblk < 4; ++dblk) {
                MFMA16(oacc[0][dblk], pa[0][n], vb[n][dblk]);
                MFMA16(oacc[1][dblk], pa[1][n], vb[n][dblk]);
            }
        __builtin_amdgcn_s_setprio(0);
        __syncthreads();   // drains GL16 (vmcnt); protects buffer reuse
        cur ^= 1;
    }
    float lm = 0.f;
#pragma unroll
    for (int q2 = 0; q2 < 2; ++q2) {
        float lsum = l_lane[q2];
        lsum += __shfl_xor(lsum, 16, 64);
        lsum += __shfl_xor(lsum, 32, 64);
        const float linv = 1.f / lsum;
#pragma unroll
        for (int j = 0; j < 4; ++j) {
            float lj = __shfl(linv, lg * 4 + j, 64);
            const size_t rowb = (size_t)((s0 + wave * 32 + q2 * 16 + lg * 4 + j) * 8 + b) * ostride + hb;
#pragma unroll
            for (int n = 0; n < 4; ++n) {
                float v = oacc[q2][n][j] * lj;
                outb[rowb + n * 16 + lr] = f2bf(v);
                lm = fmaxf(lm, fabsf(v));
            }
        }
    }
#pragma unroll
    for (int m = 1; m < 64; m <<= 1) lm = fmaxf(lm, __shfl_xor(lm, m, 64));
    if (lane == 0) smx[wave] = lm;
    __syncthreads();
    if (tid == 0) oPart[f] = fmaxf(fmaxf(smx[0], smx[1]), fmaxf(smx[2], smx[3]));
}

// ---------- layernorm over D=1024: out = LN(x + r)*g + be (+ per-block out-max) ----------
__global__ __launch_bounds__(256) void k_ln(const float* __restrict__ xf, const unsigned short* __restrict__ xb,
                                            const float* __restrict__ r,
                                            const float* __restrict__ g, const float* __restrict__ be,
                                            float* __restrict__ outf, unsigned short* __restrict__ outb,
                                            float* __restrict__ oPart) {
    const int row = blockIdx.x, tid = threadIdx.x;
    const size_t base = (size_t)row * 1024 + tid * 4;
    float x0, x1, x2, x3;
    if (xf) {
        float4 xv = *reinterpret_cast<const float4*>(xf + base);
        x0 = xv.x; x1 = xv.y; x2 = xv.z; x3 = xv.w;
    } else {
        u16x4 xv = *reinterpret_cast<const u16x4*>(xb + base);
        x0 = bf2f(xv[0]); x1 = bf2f(xv[1]); x2 = bf2f(xv[2]); x3 = bf2f(xv[3]);
    }
    float4 rv = *reinterpret_cast<const float4*>(r + base);
    float t0 = x0 + rv.x, t1 = x1 + rv.y, t2 = x2 + rv.z, t3 = x3 + rv.w;
    float s = t0 + t1 + t2 + t3;
    float ss = t0 * t0 + t1 * t1 + t2 * t2 + t3 * t3;
#pragma unroll
    for (int m = 1; m < 64; m <<= 1) { s += __shfl_xor(s, m, 64); ss += __shfl_xor(ss, m, 64); }
    __shared__ float red[8];
    __shared__ float smx[4];
    const int wave = tid >> 6, lane = tid & 63;
    if (lane == 0) { red[wave] = s; red[4 + wave] = ss; }
    __syncthreads();
    s = red[0] + red[1] + red[2] + red[3];
    ss = red[4] + red[5] + red[6] + red[7];
    const float mean = s * (1.f / 1024.f);
    const float var = ss * (1.f / 1024.f) - mean * mean;
    const float rstd = rsqrtf(var + 1e-5f);
    float4 gv = *reinterpret_cast<const float4*>(g + tid * 4);
    float4 bv = *reinterpret_cast<const float4*>(be + tid * 4);
    float o0 = (t0 - mean) * rstd * gv.x + bv.x;
    float o1 = (t1 - mean) * rstd * gv.y + bv.y;
    float o2 = (t2 - mean) * rstd * gv.z + bv.z;
    float o3 = (t3 - mean) * rstd * gv.w + bv.w;
    if (outf) {
        float4 ov = {o0, o1, o2, o3};
        *reinterpret_cast<float4*>(outf + base) = ov;
    }
    if (outb) {
        u16x4 q; q[0] = f2bf(o0); q[1] = f2bf(o1); q[2] = f2bf(o2); q[3] = f2bf(o3);
        *reinterpret_cast<u16x4*>(outb + base) = q;
    }
    if (oPart) {
        float lm = fmaxf(fmaxf(fabsf(o0), fabsf(o1)), fmaxf(fabsf(o2), fabsf(o3)));
#pragma unroll
        for (int m = 1; m < 64; m <<= 1) lm = fmaxf(lm, __shfl_xor(lm, m, 64));
        if (lane == 0) smx[wave] = lm;
        __syncthreads();
        if (tid == 0) oPart[row] = fmaxf(fmaxf(smx[0], smx[1]), fmaxf(smx[2], smx[3]));
    }
}

// ---------- host ----------
extern "C" void kernel_launch(void* const* d_in, const int* in_sizes, int n_in,
                              void* d_out, int out_size, void* d_ws, size_t ws_size,
                              hipStream_t stream) {
    const float* src   = (const float*)d_in[0];
    const float* alpha = (const float*)d_in[1];
    const float* w_in  = (const float*)d_in[2];
    const float* b_in  = (const float*)d_in[3];
    const float* w_out = (const float*)d_in[4];
    const float* b_out = (const float*)d_in[5];
    const float* w1    = (const float*)d_in[6];
    const float* b1    = (const float*)d_in[7];
    const float* w2    = (const float*)d_in[8];
    const float* b2    = (const float*)d_in[9];
    const float* g1    = (const float*)d_in[10];
    const float* be1   = (const float*)d_in[11];
    const float* g2    = (const float*)d_in[12];
    const float* be2   = (const float*)d_in[13];

    char* ws = (char*)d_ws;
    size_t off = 0;
    auto alloc = [&](size_t bytes) { size_t r = off; off += (bytes + 255) & ~(size_t)255; return r; };
    float* P              = (float*)(ws + alloc(1024));
    float* amaxv          = (float*)(ws + alloc(256));          // [0]=attnC [1]=Xbf [2]=h
    float* flashPart      = (float*)(ws + alloc(4096 * 4));
    float* lnPart         = (float*)(ws + alloc(8192 * 4));
    float* hPart          = (float*)(ws + alloc(2048 * 4));
    float* pmax           = (float*)(ws + alloc(17 * 128 * 4));
    float* psum           = (float*)(ws + alloc(17 * 128 * 4));
    signed char* WinQ8    = (signed char*)(ws + alloc((size_t)4 * 3072 * 1024));     // 12.6 MB
    signed char* WoutC8   = (signed char*)(ws + alloc((size_t)1024 * 4096));         // 4.2 MB
    float* sOut           = (float*)(ws + alloc(1024 * 4));
    signed char* W1m8     = (signed char*)(ws + alloc((size_t)4096 * 1024));         // 4.2 MB
    float* s1             = (float*)(ws + alloc(4096 * 4));
    signed char* W2m8     = (signed char*)(ws + alloc((size_t)1024 * 4096));         // 4.2 MB
    float* s2             = (float*)(ws + alloc(1024 * 4));
    float* b1m            = (float*)(ws + alloc(4096 * 4));
    float* b2m            = (float*)(ws + alloc(1024 * 4));
    float* bOm            = (float*)(ws + alloc(1024 * 4));
    signed char* Si8      = (signed char*)(ws + alloc((size_t)MM * 1024));           // 8.4 MB
    unsigned short* Xbf   = (unsigned short*)(ws + alloc((size_t)MM * 1024 * 2));    // 16.8 MB
    signed char* Xi8      = (signed char*)(ws + alloc((size_t)MM * 1024));           // 8.4 MB
    unsigned short* attnC = (unsigned short*)(ws + alloc((size_t)MM * 4096 * 2));    // 67.1 MB
    unsigned short* qkvB  = (unsigned short*)(ws + alloc((size_t)MM * 3072 * 2));    // 50.3 MB
    // overlays
    signed char* attnC8   = (signed char*)qkvB;        // 33.5 MB, qkvB dead after flash loop
    unsigned short* h     = attnC;                     // attnC dead after its q8
    signed char* h8       = (signed char*)qkvB;        // attnC8 dead after out-proj
    if (ws_size < off) return;

    float* outF = (float*)d_out;    // src2 / y scratch, then final output

    k_stats<<<dim3(128, 17), 256, 0, stream>>>(w_in, w_out, w1, w2, src, pmax, psum);
    k_params<<<1, 256, 0, stream>>>(pmax, psum, alpha, P);
    {
        int n = 4 * 3072 * 1024;
        k_quant8<<<(n + 255) / 256, 256, 0, stream>>>(w_in, WinQ8, P, 3072 * 1024, 0, n);
        k_mixq8<16, 1><<<1024, 256, 0, stream>>>(w_out, WoutC8, sOut, P, 4, 0, 1048576);
        k_mixq8<4, 0><<<4096, 256, 0, stream>>>(w1, W1m8, s1, P, 8, 1, 4194304);
        k_mixq8<16, 0><<<1024, 256, 0, stream>>>(w2, W2m8, s2, P, 12, 2, 4194304);
        k_mixb<<<(4096 + 255) / 256, 256, 0, stream>>>(b1, b1m, P, 1, 4096);
        k_mixb<<<(1024 + 255) / 256, 256, 0, stream>>>(b2, b2m, P, 2, 1024);
        k_mixb<<<(1024 + 255) / 256, 256, 0, stream>>>(b_out, bOm, P, 0, 1024);
        k_si8<<<(2097152 + 255) / 256, 256, 0, stream>>>(src, Si8, P, 2097152);
    }
    // 4 branches: i8 qkv GEMM then flash into attnC columns (+ per-block out-max)
    for (int i = 0; i < 4; ++i) {
        k_gemm_i8<<<dim3(24, 64), 256, 0, stream>>>(
            Si8, WinQ8 + (size_t)i * 3072 * 1024, qkvB, b_in + i * 3072, P, i, MM, 3072, 1024, 1, 8);
        k_fmfma<<<dim3(1024), 256, 0, stream>>>(qkvB, 3072, attnC + i * 1024, 4096,
                                                flashPart + i * 1024);
    }
    k_rmax<<<1, 256, 0, stream>>>(flashPart, 4096, amaxv + 0);
    // quantize attnC -> i8 (qkvB region), fused i8 out-proj with per-col scales
    k_q8<<<(4194304 + 255) / 256, 256, 0, stream>>>(attnC, attnC8, amaxv + 0, 4194304);
    k_gemm_i8s<float, false><<<dim3(8, 64), 256, 0, stream>>>(
        attnC8, WoutC8, outF, bOm, sOut, amaxv + 0, nullptr, MM, 1024, 4096, 4, 2);
    // x = LN(src + src2) -> bf16 + per-block max
    k_ln<<<MM, 256, 0, stream>>>(src, nullptr, outF, g1, be1, nullptr, Xbf, lnPart);
    k_rmax<<<1, 256, 0, stream>>>(lnPart, 8192, amaxv + 1);
    k_q8<<<(1048576 + 255) / 256, 256, 0, stream>>>(Xbf, Xi8, amaxv + 1, 1048576);
    // h = gelu(x @ W1m^T + b1m) -> bf16 (overlay attnC) + per-block max
    k_gemm_i8s<unsigned short, true><<<dim3(32, 64), 256, 0, stream>>>(
        Xi8, W1m8, h, b1m, s1, amaxv + 1, hPart, MM, 4096, 1024, 1, 8);
    k_rmax<<<1, 256, 0, stream>>>(hPart, 2048, amaxv + 2);
    k_q8<<<(4194304 + 255) / 256, 256, 0, stream>>>(h, h8, amaxv + 2, 4194304);
    // y = h8 @ W2m8^T + b2m (overwrites d_out)
    k_gemm_i8s<float, false><<<dim3(8, 64), 256, 0, stream>>>(
        h8, W2m8, outF, b2m, s2, amaxv + 2, nullptr, MM, 1024, 4096, 4, 2);
    // out = LN(x + y)
    k_ln<<<MM, 256, 0, stream>>>(nullptr, Xbf, outF, g2, be2, outF, nullptr, nullptr);
}

// Round 22
// 864.095 us; speedup vs baseline: 1.0119x; 1.0119x over previous
//
#include <hip/hip_runtime.h>
#include <hip/hip_bf16.h>

// ---------- types ----------
typedef __attribute__((ext_vector_type(8))) unsigned short u16x8;
typedef __attribute__((ext_vector_type(4))) unsigned short u16x4;
typedef __attribute__((ext_vector_type(2))) unsigned int   u32x2;
typedef __attribute__((ext_vector_type(4))) int            i32x4;
typedef __attribute__((ext_vector_type(8))) __bf16         bf16x8;
typedef __attribute__((ext_vector_type(4))) float          f32x4;
typedef __attribute__((address_space(3))) unsigned short   lds_us;

#define SS 1024
#define BB 8
#define DD 1024
#define HH 16
#define HDD 64
#define FF 4096
#define MM 8192   // S*B rows

// async global->LDS, 16B per lane; LDS dest is wave-uniform base + lane*16
#define GL16(g, l) __builtin_amdgcn_global_load_lds( \
    (__attribute__((address_space(1))) const void*)(g), \
    (__attribute__((address_space(3))) void*)(l), 16, 0, 0)

// LDS transpose read: lane gets 4 bf16 at elem-stride 16 from its own addr (+byte imm)
#define TRV(d, a, o) asm volatile("ds_read_b64_tr_b16 %0, %1 offset:" o : "=v"(d) : "v"(a))
// K=16 bf16 MFMA, C/D in VGPRs (gfx950 unified file)
#define MFMA16(acc, pa, vb) asm volatile("v_mfma_f32_16x16x16_bf16 %0, %1, %2, %0" \
    : "+v"(acc) : "v"(pa), "v"(vb))

__device__ __forceinline__ float bf2f(unsigned short u) {
    return __uint_as_float(((unsigned int)u) << 16);
}
__device__ __forceinline__ unsigned short f2bf(float f) {
    return __builtin_bit_cast(unsigned short, (__bf16)f);   // HW RNE cvt
}
__device__ __forceinline__ float quantv(float w, float som, float qm) {
    if (qm == 0.f) {  // 1-bit: sign(w)*mean|w|
        float sgn = (w > 0.f) ? 1.f : ((w < 0.f) ? -1.f : 0.f);
        return sgn * som;
    }
    if (som == 0.f) return 0.f;
    float q = rintf(w / som);
    q = fminf(fmaxf(q, -qm - 1.f), qm);
    return q * som;
}

// ---------- stats: per-tensor max|.|, sum|.| (4-deep load pipeline; R19-proven) ----------
__global__ __launch_bounds__(256) void k_stats(const float* __restrict__ w_in, const float* __restrict__ w_out,
                                               const float* __restrict__ w1, const float* __restrict__ w2,
                                               const float* __restrict__ src,
                                               float* __restrict__ pmax, float* __restrict__ psum) {
    const int t = blockIdx.y, blk = blockIdx.x, tid = threadIdx.x;
    const float* base; int n;
    if (t < 4)       { base = w_in  + (size_t)t * 3145728;     n = 3145728; }
    else if (t < 8)  { base = w_out + (size_t)(t-4) * 1048576; n = 1048576; }
    else if (t < 12) { base = w1    + (size_t)(t-8) * 4194304; n = 4194304; }
    else if (t < 16) { base = w2    + (size_t)(t-12) * 4194304; n = 4194304; }
    else             { base = src;                             n = 8388608; }
    const int per = (n >> 2) >> 8;   // float4s per block; always divisible by 1024
    const float4* bptr = reinterpret_cast<const float4*>(base) + (size_t)blk * per;
    float mx0 = 0.f, mx1 = 0.f, mx2 = 0.f, mx3 = 0.f;
    float sm0 = 0.f, sm1 = 0.f, sm2 = 0.f, sm3 = 0.f;
    for (int i = tid; i < per; i += 1024) {   // 4 independent loads in flight
        float4 a = bptr[i];
        float4 b4 = bptr[i + 256];
        float4 c = bptr[i + 512];
        float4 d = bptr[i + 768];
        float a0 = fabsf(a.x), a1 = fabsf(a.y), a2 = fabsf(a.z), a3 = fabsf(a.w);
        float b0 = fabsf(b4.x), b1 = fabsf(b4.y), b2 = fabsf(b4.z), b3 = fabsf(b4.w);
        float c0 = fabsf(c.x), c1 = fabsf(c.y), c2 = fabsf(c.z), c3 = fabsf(c.w);
        float d0 = fabsf(d.x), d1 = fabsf(d.y), d2 = fabsf(d.z), d3 = fabsf(d.w);
        mx0 = fmaxf(mx0, fmaxf(fmaxf(a0, a1), fmaxf(a2, a3)));
        mx1 = fmaxf(mx1, fmaxf(fmaxf(b0, b1), fmaxf(b2, b3)));
        mx2 = fmaxf(mx2, fmaxf(fmaxf(c0, c1), fmaxf(c2, c3)));
        mx3 = fmaxf(mx3, fmaxf(fmaxf(d0, d1), fmaxf(d2, d3)));
        sm0 += (a0 + a1) + (a2 + a3);
        sm1 += (b0 + b1) + (b2 + b3);
        sm2 += (c0 + c1) + (c2 + c3);
        sm3 += (d0 + d1) + (d2 + d3);
    }
    float vmax = fmaxf(fmaxf(mx0, mx1), fmaxf(mx2, mx3));
    float vsum = (sm0 + sm1) + (sm2 + sm3);
#pragma unroll
    for (int m = 1; m < 64; m <<= 1) { vmax = fmaxf(vmax, __shfl_xor(vmax, m, 64)); vsum += __shfl_xor(vsum, m, 64); }
    __shared__ float sm[4], su[4];
    const int wave = tid >> 6, lane = tid & 63;
    if (lane == 0) { sm[wave] = vmax; su[wave] = vsum; }
    __syncthreads();
    if (tid == 0) {
        pmax[t * 256 + blk] = fmaxf(fmaxf(sm[0], sm[1]), fmaxf(sm[2], sm[3]));
        psum[t * 256 + blk] = (su[0] + su[1]) + (su[2] + su[3]);
    }
}

// ---------- params: final reduce + softmax(alpha); P[50] = src absmax/127 ----------
__global__ __launch_bounds__(256) void k_params(const float* __restrict__ pmax, const float* __restrict__ psum,
                                                const float* __restrict__ alpha, float* __restrict__ P) {
    __shared__ float rm[256], rs[256];
    const int tid = threadIdx.x;
    for (int t = 0; t < 17; ++t) {
        rm[tid] = pmax[t * 256 + tid];
        rs[tid] = psum[t * 256 + tid];
        __syncthreads();
        for (int s = 128; s > 0; s >>= 1) {
            if (tid < s) { rm[tid] = fmaxf(rm[tid], rm[tid + s]); rs[tid] += rs[tid + s]; }
            __syncthreads();
        }
        if (tid == 0) {
            if (t == 16) {
                P[50] = rm[0] * (1.f / 127.f);
            } else {
                const int nbits[4] = {1, 2, 4, 8};
                const int nb = nbits[t & 3];
                float nsize = (t < 4) ? 3145728.f : ((t < 8) ? 1048576.f : 4194304.f);
                if (nb == 1) { P[16 + 2*t] = rs[0] / nsize; P[17 + 2*t] = 0.f; }
                else { float qm = (float)((1 << (nb - 1)) - 1); P[16 + 2*t] = rm[0] / qm; P[17 + 2*t] = qm; }
            }
        }
        __syncthreads();
    }
    if (tid < 3) {
        float a[4], mx = -1e30f;
#pragma unroll
        for (int i = 0; i < 4; ++i) { a[i] = alpha[tid * 4 + i]; mx = fmaxf(mx, a[i]); }
        float e[4], ssum = 0.f;
#pragma unroll
        for (int i = 0; i < 4; ++i) { e[i] = expf(a[i] - mx); ssum += e[i]; }
#pragma unroll
        for (int i = 0; i < 4; ++i) P[tid * 4 + i] = e[i] / ssum;
    }
}

// ---------- one-block max reduce: out = max(part[0..n)) ----------
__global__ __launch_bounds__(256) void k_rmax(const float* __restrict__ part, int n, float* __restrict__ out) {
    const int tid = threadIdx.x;
    float m = 0.f;
    for (int i = tid; i < n; i += 256) m = fmaxf(m, part[i]);
#pragma unroll
    for (int s = 1; s < 64; s <<= 1) m = fmaxf(m, __shfl_xor(m, s, 64));
    __shared__ float sm[4];
    const int wave = tid >> 6, lane = tid & 63;
    if (lane == 0) sm[wave] = m;
    __syncthreads();
    if (tid == 0) *out = fmaxf(fmaxf(sm[0], sm[1]), fmaxf(sm[2], sm[3]));
}

// ---------- quantize in-proj weights -> i8 (integer part is EXACT per reference) ----------
__global__ __launch_bounds__(256) void k_quant8(const float* __restrict__ w, signed char* __restrict__ out,
                                                const float* __restrict__ P, int per_tensor, int tbase, int ntot) {
    int i = blockIdx.x * 256 + threadIdx.x;
    if (i >= ntot) return;
    int t = tbase + i / per_tensor;
    float som = P[16 + 2*t], qm = P[17 + 2*t];
    float v;
    float x = w[i];
    if (qm == 0.f)      v = (x > 0.f) ? 1.f : ((x < 0.f) ? -1.f : 0.f);
    else if (som == 0.f) v = 0.f;
    else                v = fminf(fmaxf(rintf(x / som), -qm - 1.f), qm);
    out[i] = (signed char)(int)v;
}

// ---------- quantize src -> i8 with per-tensor scale P[50] ----------
__global__ __launch_bounds__(256) void k_si8(const float* __restrict__ in, signed char* __restrict__ out,
                                             const float* __restrict__ P, int n4) {
    int i = blockIdx.x * 256 + threadIdx.x;
    if (i >= n4) return;
    const float sa = P[50];
    const float inv = (sa > 0.f) ? 1.f / sa : 0.f;
    float4 v = reinterpret_cast<const float4*>(in)[i];
    char4 o;
    o.x = (signed char)(int)fminf(fmaxf(rintf(v.x * inv), -127.f), 127.f);
    o.y = (signed char)(int)fminf(fmaxf(rintf(v.y * inv), -127.f), 127.f);
    o.z = (signed char)(int)fminf(fmaxf(rintf(v.z * inv), -127.f), 127.f);
    o.w = (signed char)(int)fminf(fmaxf(rintf(v.w * inv), -127.f), 127.f);
    reinterpret_cast<char4*>(out)[i] = o;
}

// ---------- mixed weights -> per-row i8 + row scale ----------
template <int NE, int MODE>
__global__ __launch_bounds__(256) void k_mixq8(const float* __restrict__ w, signed char* __restrict__ out,
                                               float* __restrict__ sB, const float* __restrict__ P,
                                               int tbase, int prow, size_t sz) {
    const int row = blockIdx.x, tid = threadIdx.x;
    const int L = NE * 256;
    float v[NE];
    float lm = 0.f;
#pragma unroll
    for (int j = 0; j < NE; ++j) {
        int k = j * 256 + tid;
        float acc;
        if (MODE == 0) {
            acc = 0.f;
#pragma unroll
            for (int br = 0; br < 4; ++br) {
                int t = tbase + br;
                acc += P[prow * 4 + br] * quantv(w[(size_t)br * sz + (size_t)row * L + k], P[16 + 2*t], P[17 + 2*t]);
            }
        } else {
            int i = k >> 10, e = k & 1023;
            int t = tbase + i;
            acc = P[i] * quantv(w[(size_t)i * sz + (size_t)row * 1024 + e], P[16 + 2*t], P[17 + 2*t]);
        }
        v[j] = acc;
        lm = fmaxf(lm, fabsf(acc));
    }
#pragma unroll
    for (int m = 1; m < 64; m <<= 1) lm = fmaxf(lm, __shfl_xor(lm, m, 64));
    __shared__ float sm[4];
    const int wave = tid >> 6, lane = tid & 63;
    if (lane == 0) sm[wave] = lm;
    __syncthreads();
    lm = fmaxf(fmaxf(sm[0], sm[1]), fmaxf(sm[2], sm[3]));
    if (tid == 0) sB[row] = lm * (1.f / 127.f);
    const float inv = (lm > 0.f) ? 127.f / lm : 0.f;
#pragma unroll
    for (int j = 0; j < NE; ++j)
        out[(size_t)row * L + j * 256 + tid] =
            (signed char)(int)fminf(fmaxf(rintf(v[j] * inv), -127.f), 127.f);
}

__global__ __launch_bounds__(256) void k_mixb(const float* __restrict__ b, float* __restrict__ out,
                                              const float* __restrict__ P, int prow, int n) {
    int i = blockIdx.x * 256 + threadIdx.x;
    if (i >= n) return;
    float acc = 0.f;
#pragma unroll
    for (int br = 0; br < 4; ++br) acc += P[prow * 4 + br] * b[(size_t)br * n + i];
    out[i] = acc;
}

// ---------- bf16 buffer -> i8 with scale = *amax/127 ----------
__global__ __launch_bounds__(256) void k_q8(const unsigned short* __restrict__ in, signed char* __restrict__ out,
                                            const float* __restrict__ amax, int n8) {
    int i = blockIdx.x * 256 + threadIdx.x;
    if (i >= n8) return;
    const float am = *amax;
    const float inv = (am > 0.f) ? 127.f / am : 0.f;
    u16x8 v = reinterpret_cast<const u16x8*>(in)[i];
    union { signed char c[8]; unsigned long long u; } r;
#pragma unroll
    for (int e = 0; e < 8; ++e) {
        float f = bf2f(v[e]) * inv;
        r.c[e] = (signed char)(int)fminf(fmaxf(rintf(f), -127.f), 127.f);
    }
    reinterpret_cast<unsigned long long*>(out)[i] = r.u;
}

// ---------- i8 GEMM, per-tensor scale pair (qkv; proven in R9) ----------
__global__ __launch_bounds__(256) void k_gemm_i8(const signed char* __restrict__ A,
                                                 const signed char* __restrict__ Bw,
                                                 unsigned short* __restrict__ C,
                                                 const float* __restrict__ bias,
                                                 const float* __restrict__ P, int tIdx,
                                                 int M, int N, int K, int XM, int XN) {
    const int gx = gridDim.x, gy = gridDim.y;
    const int flat = blockIdx.x + gx * blockIdx.y;
    const int xcd = flat & 7, r = flat >> 3;
    const int nloc = gx / XN, mloc = gy / XM;
    const int cm = xcd / XN, cn = xcd - cm * XN;
    const int by = cm * mloc + r / nloc;
    const int bx = cn * nloc + (r - (r / nloc) * nloc);

    __shared__ signed char As[2][128 * 128];
    __shared__ signed char Bs[2][128 * 128];
    const int tid = threadIdx.x;
    const int m0 = by * 128, n0 = bx * 128;
    const int lane = tid & 63, wave = tid >> 6;
    const int wr = wave >> 1, wc = wave & 1;
    const int lr = lane & 15, lg = lane >> 4;
    const int rsub = lane >> 3;
    const int csub = ((lane & 7) ^ rsub) * 16;
    const size_t aoff = (size_t)(m0 + rsub) * K + csub;
    const size_t boff = (size_t)(n0 + rsub) * K + csub;

    i32x4 acc[4][4];
#pragma unroll
    for (int m = 0; m < 4; ++m)
#pragma unroll
        for (int n = 0; n < 4; ++n) acc[m][n] = (i32x4){0, 0, 0, 0};

    auto stage = [&](int buf, int k0) {
#pragma unroll
        for (int it = 0; it < 4; ++it) {
            const int g = it * 4 + wave;
            GL16(A + aoff + (size_t)g * 8 * K + k0, &As[buf][g * 1024]);
            GL16(Bw + boff + (size_t)g * 8 * K + k0, &Bs[buf][g * 1024]);
        }
    };
    auto compute = [&](int buf) {
#pragma unroll
        for (int kh = 0; kh < 2; ++kh) {
            i32x4 af[4], bfr[4];
#pragma unroll
            for (int m = 0; m < 4; ++m) {
                int row = wr * 64 + m * 16 + lr;
                int cidx = (kh * 4 + lg) ^ (lr & 7);
                af[m] = *reinterpret_cast<const i32x4*>(&As[buf][row * 128 + cidx * 16]);
            }
#pragma unroll
            for (int n = 0; n < 4; ++n) {
                int row = wc * 64 + n * 16 + lr;
                int cidx = (kh * 4 + lg) ^ (lr & 7);
                bfr[n] = *reinterpret_cast<const i32x4*>(&Bs[buf][row * 128 + cidx * 16]);
            }
#pragma unroll
            for (int m = 0; m < 4; ++m)
#pragma unroll
                for (int n = 0; n < 4; ++n)
                    acc[m][n] = __builtin_amdgcn_mfma_i32_16x16x64_i8(
                        af[m], bfr[n], acc[m][n], 0, 0, 0);
        }
    };

    stage(0, 0);
    __syncthreads();
    int cur = 0;
    for (int k0 = 128; k0 < K; k0 += 128) {
        stage(cur ^ 1, k0);
        compute(cur);
        __syncthreads();
        cur ^= 1;
    }
    compute(cur);

    const float sab = P[50] * P[16 + 2 * tIdx];
#pragma unroll
    for (int n = 0; n < 4; ++n) {
        const int col = n0 + wc * 64 + n * 16 + lr;
        const float bv = bias[col];
#pragma unroll
        for (int m = 0; m < 4; ++m) {
#pragma unroll
            for (int j = 0; j < 4; ++j) {
                const int row = m0 + wr * 64 + m * 16 + lg * 4 + j;
                float v = (float)acc[m][n][j] * sab + bv;
                C[(size_t)row * N + col] = f2bf(v);
            }
        }
    }
}

// ---------- i8 GEMM with per-column B scale + scalar A scale; GELU; per-block out-max ----------
__device__ __forceinline__ void store_out(float* C, size_t idx, float v) { C[idx] = v; }
__device__ __forceinline__ void store_out(unsigned short* C, size_t idx, float v) { C[idx] = f2bf(v); }

template <typename OutT, bool GELU>
__global__ __launch_bounds__(256) void k_gemm_i8s(const signed char* __restrict__ A,
                                                  const signed char* __restrict__ Bw,
                                                  OutT* __restrict__ C,
                                                  const float* __restrict__ bias,
                                                  const float* __restrict__ sB,
                                                  const float* __restrict__ aAm,
                                                  float* __restrict__ oPart,
                                                  int M, int N, int K, int XM, int XN) {
    const int gx = gridDim.x, gy = gridDim.y;
    const int flat = blockIdx.x + gx * blockIdx.y;
    const int xcd = flat & 7, r = flat >> 3;
    const int nloc = gx / XN, mloc = gy / XM;
    const int cm = xcd / XN, cn = xcd - cm * XN;
    const int by = cm * mloc + r / nloc;
    const int bx = cn * nloc + (r - (r / nloc) * nloc);

    __shared__ signed char As[2][128 * 128];
    __shared__ signed char Bs[2][128 * 128];
    __shared__ float smx[4];
    const int tid = threadIdx.x;
    const int m0 = by * 128, n0 = bx * 128;
    const int lane = tid & 63, wave = tid >> 6;
    const int wr = wave >> 1, wc = wave & 1;
    const int lr = lane & 15, lg = lane >> 4;
    const int rsub = lane >> 3;
    const int csub = ((lane & 7) ^ rsub) * 16;
    const size_t aoff = (size_t)(m0 + rsub) * K + csub;
    const size_t boff = (size_t)(n0 + rsub) * K + csub;

    i32x4 acc[4][4];
#pragma unroll
    for (int m = 0; m < 4; ++m)
#pragma unroll
        for (int n = 0; n < 4; ++n) acc[m][n] = (i32x4){0, 0, 0, 0};

    auto stage = [&](int buf, int k0) {
#pragma unroll
        for (int it = 0; it < 4; ++it) {
            const int g = it * 4 + wave;
            GL16(A + aoff + (size_t)g * 8 * K + k0, &As[buf][g * 1024]);
            GL16(Bw + boff + (size_t)g * 8 * K + k0, &Bs[buf][g * 1024]);
        }
    };
    auto compute = [&](int buf) {
#pragma unroll
        for (int kh = 0; kh < 2; ++kh) {
            i32x4 af[4], bfr[4];
#pragma unroll
            for (int m = 0; m < 4; ++m) {
                int row = wr * 64 + m * 16 + lr;
                int cidx = (kh * 4 + lg) ^ (lr & 7);
                af[m] = *reinterpret_cast<const i32x4*>(&As[buf][row * 128 + cidx * 16]);
            }
#pragma unroll
            for (int n = 0; n < 4; ++n) {
                int row = wc * 64 + n * 16 + lr;
                int cidx = (kh * 4 + lg) ^ (lr & 7);
                bfr[n] = *reinterpret_cast<const i32x4*>(&Bs[buf][row * 128 + cidx * 16]);
            }
#pragma unroll
            for (int m = 0; m < 4; ++m)
#pragma unroll
                for (int n = 0; n < 4; ++n)
                    acc[m][n] = __builtin_amdgcn_mfma_i32_16x16x64_i8(
                        af[m], bfr[n], acc[m][n], 0, 0, 0);
        }
    };

    stage(0, 0);
    __syncthreads();
    int cur = 0;
    for (int k0 = 128; k0 < K; k0 += 128) {
        stage(cur ^ 1, k0);
        compute(cur);
        __syncthreads();
        cur ^= 1;
    }
    compute(cur);

    const float sA = (*aAm) * (1.f / 127.f);
    float lm = 0.f;
#pragma unroll
    for (int n = 0; n < 4; ++n) {
        const int col = n0 + wc * 64 + n * 16 + lr;
        const float sc = sA * sB[col];
        const float bv = bias ? bias[col] : 0.f;
#pragma unroll
        for (int m = 0; m < 4; ++m) {
#pragma unroll
            for (int j = 0; j < 4; ++j) {
                const int row = m0 + wr * 64 + m * 16 + lg * 4 + j;
                float v = (float)acc[m][n][j] * sc + bv;
                if (GELU) v = 0.5f * v * (1.f + erff(v * 0.70710678118654752f));
                store_out(C, (size_t)row * N + col, v);
                if (oPart) lm = fmaxf(lm, fabsf(v));
            }
        }
    }
    if (oPart) {
#pragma unroll
        for (int m = 1; m < 64; m <<= 1) lm = fmaxf(lm, __shfl_xor(lm, m, 64));
        if (lane == 0) smx[wave] = lm;
        __syncthreads();
        if (tid == 0) oPart[flat] = fmaxf(fmaxf(smx[0], smx[1]), fmaxf(smx[2], smx[3]));
    }
}

// ---------- MFMA flash attention: zero-shuffle PV, phase-split q2 streams (R19-proven) ----------
__global__ __launch_bounds__(256) void k_fmfma(const unsigned short* __restrict__ qkvb, int qstride,
                                               unsigned short* __restrict__ outb, int ostride,
                                               float* __restrict__ oPart) {
    __shared__ unsigned short Ks[2][4096];
    __shared__ unsigned short Vs[2][4096];
    __shared__ float smx[4];
    const int tid = threadIdx.x;
    const int lane = tid & 63, wave = tid >> 6;
    const int lr = lane & 15, lg = lane >> 4;
    // grid 1024 = 8 xcd x 16 bh x 8 qidx: all 8 q-blocks of one bh on one XCD
    const int f = blockIdx.x;
    const int bh = (f & 7) * 16 + ((f >> 3) & 15);
    const int s0 = (f >> 7) * 128;
    const int b = bh >> 4, hh = bh & 15;
    const int hb = hh * 64;

    // Q fragments: 2 per wave (rows s0 + wave*32 + q2*16 + lr)
    u16x8 qf[2][2];
#pragma unroll
    for (int q2 = 0; q2 < 2; ++q2) {
        const size_t qb = (size_t)((s0 + wave * 32 + q2 * 16 + lr) * 8 + b) * qstride + hb;
#pragma unroll
        for (int ks = 0; ks < 2; ++ks)
            qf[q2][ks] = *reinterpret_cast<const u16x8*>(qkvb + qb + ks * 32 + lg * 8);
    }
    // staging sources (per-thread, kt-independent parts)
    size_t kOff[2], vOff[2];
#pragma unroll
    for (int it = 0; it < 2; ++it) {
        const int g = it * 256 + tid;
        const int krow = g >> 3, kchs = g & 7;
        kOff[it] = (size_t)(krow * 8 + b) * qstride + 1024 + hb + ((kchs ^ (krow & 7)) * 8);
        const int dblk = (g >> 7) & 3, khi = (g >> 5) & 3, kmid = (g >> 3) & 3, klo = (g >> 1) & 3, dh = g & 1;
        const int vkey = khi * 16 + kmid * 4 + klo;
        vOff[it] = (size_t)(vkey * 8 + b) * qstride + 2048 + hb + dblk * 16 + dh * 8;
    }
    // TRV addresses as AS3 pointers (true 32-bit LDS offsets)
    const lds_us* va0 = (lds_us*)&Vs[0][lg * 64 + lr];
    const lds_us* va1 = (lds_us*)&Vs[1][lg * 64 + lr];

    float m_old[2] = {-1e30f, -1e30f};
    float l_lane[2] = {0.f, 0.f};
    f32x4 oacc[2][4];
#pragma unroll
    for (int q2 = 0; q2 < 2; ++q2)
#pragma unroll
        for (int n = 0; n < 4; ++n) oacc[q2][n] = (f32x4){0.f, 0.f, 0.f, 0.f};

    auto stage = [&](int buf, int kt) {
        const size_t ktoff = (size_t)kt * 512 * qstride;
#pragma unroll
        for (int it = 0; it < 2; ++it) {
            GL16(qkvb + kOff[it] + ktoff, &Ks[buf][it * 2048 + wave * 512]);
            GL16(qkvb + vOff[it] + ktoff, &Vs[buf][it * 2048 + wave * 512]);
        }
    };

    stage(0, 0);
    __syncthreads();
    int cur = 0;
    for (int kt = 0; kt < 16; ++kt) {
        if (kt < 15) stage(cur ^ 1, kt + 1);   // prefetch; drained by barrier below
        // V tr-read fragments: vb[n][dblk], byte imm = dblk*2048+n*512
        const lds_us* va = cur ? va1 : va0;
        u32x2 vb[4][4];
        TRV(vb[0][0], va, "0");    TRV(vb[0][1], va, "2048"); TRV(vb[0][2], va, "4096"); TRV(vb[0][3], va, "6144");
        TRV(vb[1][0], va, "512");  TRV(vb[1][1], va, "2560"); TRV(vb[1][2], va, "4608"); TRV(vb[1][3], va, "6656");
        TRV(vb[2][0], va, "1024"); TRV(vb[2][1], va, "3072"); TRV(vb[2][2], va, "5120"); TRV(vb[2][3], va, "7168");
        TRV(vb[3][0], va, "1536"); TRV(vb[3][1], va, "3584"); TRV(vb[3][2], va, "5632"); TRV(vb[3][3], va, "7680");
        asm volatile("s_waitcnt lgkmcnt(0)" ::: "memory");
        __builtin_amdgcn_sched_barrier(0);
        // ---- phase 1: QK^T for BOTH q2, sharing each Ks ds_read ----
        f32x4 sacc[2][4];
#pragma unroll
        for (int q2 = 0; q2 < 2; ++q2)
#pragma unroll
            for (int n = 0; n < 4; ++n) sacc[q2][n] = (f32x4){0.f, 0.f, 0.f, 0.f};
        __builtin_amdgcn_s_setprio(1);
#pragma unroll
        for (int ks = 0; ks < 2; ++ks) {
#pragma unroll
            for (int n = 0; n < 4; ++n) {
                int row = n * 16 + lr;
                int cidx = (ks * 4 + lg) ^ (lr & 7);
                u16x8 kf = *reinterpret_cast<const u16x8*>(&Ks[cur][row * 64 + cidx * 8]);
                sacc[0][n] = __builtin_amdgcn_mfma_f32_16x16x32_bf16(
                    __builtin_bit_cast(bf16x8, kf), __builtin_bit_cast(bf16x8, qf[0][ks]),
                    sacc[0][n], 0, 0, 0);
                sacc[1][n] = __builtin_amdgcn_mfma_f32_16x16x32_bf16(
                    __builtin_bit_cast(bf16x8, kf), __builtin_bit_cast(bf16x8, qf[1][ks]),
                    sacc[1][n], 0, 0, 0);
            }
        }
        __builtin_amdgcn_s_setprio(0);
        // ---- phase 2: softmax both q2 (independent chains), pack into pa ----
        u32x2 pa[2][4];
        float corr2[2];
#pragma unroll
        for (int q2 = 0; q2 < 2; ++q2) {
            float pmax = -1e30f;
#pragma unroll
            for (int n = 0; n < 4; ++n)
#pragma unroll
                for (int j = 0; j < 4; ++j) { sacc[q2][n][j] *= 0.125f; pmax = fmaxf(pmax, sacc[q2][n][j]); }
            pmax = fmaxf(pmax, __shfl_xor(pmax, 16, 64));
            pmax = fmaxf(pmax, __shfl_xor(pmax, 32, 64));
            const float m_new = fmaxf(m_old[q2], pmax);
            const float corr = __expf(m_old[q2] - m_new);
            float psum = 0.f;
#pragma unroll
            for (int n = 0; n < 4; ++n) {
                float e0 = __expf(sacc[q2][n][0] - m_new);
                float e1 = __expf(sacc[q2][n][1] - m_new);
                float e2 = __expf(sacc[q2][n][2] - m_new);
                float e3 = __expf(sacc[q2][n][3] - m_new);
                psum += (e0 + e1) + (e2 + e3);
                pa[q2][n][0] = (unsigned)f2bf(e0) | ((unsigned)f2bf(e1) << 16);
                pa[q2][n][1] = (unsigned)f2bf(e2) | ((unsigned)f2bf(e3) << 16);
            }
            l_lane[q2] = l_lane[q2] * corr + psum;
            m_old[q2] = m_new;
            corr2[q2] = corr;
        }
        // ---- phase 3: rescale O rows both q2 ----
#pragma unroll
        for (int j = 0; j < 4; ++j) {
            float cj0 = __shfl(corr2[0], lg * 4 + j, 64);
            float cj1 = __shfl(corr2[1], lg * 4 + j, 64);
#pragma unroll
            for (int n = 0; n < 4; ++n) { oacc[0][n][j] *= cj0; oacc[1][n][j] *= cj1; }
        }
        // ---- phase 4: PV interleaved across q2 (two independent MFMA chains) ----
        __builtin_amdgcn_s_setprio(1);
#pragma unroll
        for (int n = 0; n < 4; ++n)
#pragma unroll
            for (int dblk = 0; dblk < 4; ++dblk) {
                MFMA16(oacc[0][dblk], pa[0][n], vb[n][dblk]);
                MFMA16(oacc[1][dblk], pa[1][n], vb[n][dblk]);
            }
        __builtin_amdgcn_s_setprio(0);
        __syncthreads();   // drains GL16 (vmcnt); protects buffer reuse
        cur ^= 1;
    }
    float lm = 0.f;
#pragma unroll
    for (int q2 = 0; q2 < 2; ++q2) {
        float lsum = l_lane[q2];
        lsum += __shfl_xor(lsum, 16, 64);
        lsum += __shfl_xor(lsum, 32, 64);
        const float linv = 1.f / lsum;
#pragma unroll
        for (int j = 0; j < 4; ++j) {
            float lj = __shfl(linv, lg * 4 + j, 64);
            const size_t rowb = (size_t)((s0 + wave * 32 + q2 * 16 + lg * 4 + j) * 8 + b) * ostride + hb;
#pragma unroll
            for (int n = 0; n < 4; ++n) {
                float v = oacc[q2][n][j] * lj;
                outb[rowb + n * 16 + lr] = f2bf(v);
                lm = fmaxf(lm, fabsf(v));
            }
        }
    }
#pragma unroll
    for (int m = 1; m < 64; m <<= 1) lm = fmaxf(lm, __shfl_xor(lm, m, 64));
    if (lane == 0) smx[wave] = lm;
    __syncthreads();
    if (tid == 0) oPart[f] = fmaxf(fmaxf(smx[0], smx[1]), fmaxf(smx[2], smx[3]));
}

// ---------- layernorm over D=1024: out = LN(x + r)*g + be (+ per-block out-max) ----------
__global__ __launch_bounds__(256) void k_ln(const float* __restrict__ xf, const unsigned short* __restrict__ xb,
                                            const float* __restrict__ r,
                                            const float* __restrict__ g, const float* __restrict__ be,
                                            float* __restrict__ outf, unsigned short* __restrict__ outb,
                                            float* __restrict__ oPart) {
    const int row = blockIdx.x, tid = threadIdx.x;
    const size_t base = (size_t)row * 1024 + tid * 4;
    float x0, x1, x2, x3;
    if (xf) {
        float4 xv = *reinterpret_cast<const float4*>(xf + base);
        x0 = xv.x; x1 = xv.y; x2 = xv.z; x3 = xv.w;
    } else {
        u16x4 xv = *reinterpret_cast<const u16x4*>(xb + base);
        x0 = bf2f(xv[0]); x1 = bf2f(xv[1]); x2 = bf2f(xv[2]); x3 = bf2f(xv[3]);
    }
    float4 rv = *reinterpret_cast<const float4*>(r + base);
    float t0 = x0 + rv.x, t1 = x1 + rv.y, t2 = x2 + rv.z, t3 = x3 + rv.w;
    float s = t0 + t1 + t2 + t3;
    float ss = t0 * t0 + t1 * t1 + t2 * t2 + t3 * t3;
#pragma unroll
    for (int m = 1; m < 64; m <<= 1) { s += __shfl_xor(s, m, 64); ss += __shfl_xor(ss, m, 64); }
    __shared__ float red[8];
    __shared__ float smx[4];
    const int wave = tid >> 6, lane = tid & 63;
    if (lane == 0) { red[wave] = s; red[4 + wave] = ss; }
    __syncthreads();
    s = red[0] + red[1] + red[2] + red[3];
    ss = red[4] + red[5] + red[6] + red[7];
    const float mean = s * (1.f / 1024.f);
    const float var = ss * (1.f / 1024.f) - mean * mean;
    const float rstd = rsqrtf(var + 1e-5f);
    float4 gv = *reinterpret_cast<const float4*>(g + tid * 4);
    float4 bv = *reinterpret_cast<const float4*>(be + tid * 4);
    float o0 = (t0 - mean) * rstd * gv.x + bv.x;
    float o1 = (t1 - mean) * rstd * gv.y + bv.y;
    float o2 = (t2 - mean) * rstd * gv.z + bv.z;
    float o3 = (t3 - mean) * rstd * gv.w + bv.w;
    if (outf) {
        float4 ov = {o0, o1, o2, o3};
        *reinterpret_cast<float4*>(outf + base) = ov;
    }
    if (outb) {
        u16x4 q; q[0] = f2bf(o0); q[1] = f2bf(o1); q[2] = f2bf(o2); q[3] = f2bf(o3);
        *reinterpret_cast<u16x4*>(outb + base) = q;
    }
    if (oPart) {
        float lm = fmaxf(fmaxf(fabsf(o0), fabsf(o1)), fmaxf(fabsf(o2), fabsf(o3)));
#pragma unroll
        for (int m = 1; m < 64; m <<= 1) lm = fmaxf(lm, __shfl_xor(lm, m, 64));
        if (lane == 0) smx[wave] = lm;
        __syncthreads();
        if (tid == 0) oPart[row] = fmaxf(fmaxf(smx[0], smx[1]), fmaxf(smx[2], smx[3]));
    }
}

// ---------- host ----------
extern "C" void kernel_launch(void* const* d_in, const int* in_sizes, int n_in,
                              void* d_out, int out_size, void* d_ws, size_t ws_size,
                              hipStream_t stream) {
    const float* src   = (const float*)d_in[0];
    const float* alpha = (const float*)d_in[1];
    const float* w_in  = (const float*)d_in[2];
    const float* b_in  = (const float*)d_in[3];
    const float* w_out = (const float*)d_in[4];
    const float* b_out = (const float*)d_in[5];
    const float* w1    = (const float*)d_in[6];
    const float* b1    = (const float*)d_in[7];
    const float* w2    = (const float*)d_in[8];
    const float* b2    = (const float*)d_in[9];
    const float* g1    = (const float*)d_in[10];
    const float* be1   = (const float*)d_in[11];
    const float* g2    = (const float*)d_in[12];
    const float* be2   = (const float*)d_in[13];

    char* ws = (char*)d_ws;
    size_t off = 0;
    auto alloc = [&](size_t bytes) { size_t r = off; off += (bytes + 255) & ~(size_t)255; return r; };
    float* P              = (float*)(ws + alloc(1024));
    float* amaxv          = (float*)(ws + alloc(256));          // [0]=attnC [1]=Xbf [2]=h
    float* flashPart      = (float*)(ws + alloc(4096 * 4));
    float* lnPart         = (float*)(ws + alloc(8192 * 4));
    float* hPart          = (float*)(ws + alloc(2048 * 4));
    float* pmax           = (float*)(ws + alloc(17 * 256 * 4));
    float* psum           = (float*)(ws + alloc(17 * 256 * 4));
    signed char* WinQ8    = (signed char*)(ws + alloc((size_t)4 * 3072 * 1024));     // 12.6 MB
    signed char* WoutC8   = (signed char*)(ws + alloc((size_t)1024 * 4096));         // 4.2 MB
    float* sOut           = (float*)(ws + alloc(1024 * 4));
    signed char* W1m8     = (signed char*)(ws + alloc((size_t)4096 * 1024));         // 4.2 MB
    float* s1             = (float*)(ws + alloc(4096 * 4));
    signed char* W2m8     = (signed char*)(ws + alloc((size_t)1024 * 4096));         // 4.2 MB
    float* s2             = (float*)(ws + alloc(1024 * 4));
    float* b1m            = (float*)(ws + alloc(4096 * 4));
    float* b2m            = (float*)(ws + alloc(1024 * 4));
    float* bOm            = (float*)(ws + alloc(1024 * 4));
    signed char* Si8      = (signed char*)(ws + alloc((size_t)MM * 1024));           // 8.4 MB
    unsigned short* Xbf   = (unsigned short*)(ws + alloc((size_t)MM * 1024 * 2));    // 16.8 MB
    signed char* Xi8      = (signed char*)(ws + alloc((size_t)MM * 1024));           // 8.4 MB
    unsigned short* attnC = (unsigned short*)(ws + alloc((size_t)MM * 4096 * 2));    // 67.1 MB
    unsigned short* qkvB  = (unsigned short*)(ws + alloc((size_t)MM * 3072 * 2));    // 50.3 MB
    // overlays
    signed char* attnC8   = (signed char*)qkvB;        // 33.5 MB, qkvB dead after flash loop
    unsigned short* h     = attnC;                     // attnC dead after its q8
    signed char* h8       = (signed char*)qkvB;        // attnC8 dead after out-proj
    if (ws_size < off) return;

    float* outF = (float*)d_out;    // src2 / y scratch, then final output

    k_stats<<<dim3(256, 17), 256, 0, stream>>>(w_in, w_out, w1, w2, src, pmax, psum);
    k_params<<<1, 256, 0, stream>>>(pmax, psum, alpha, P);
    {
        int n = 4 * 3072 * 1024;
        k_quant8<<<(n + 255) / 256, 256, 0, stream>>>(w_in, WinQ8, P, 3072 * 1024, 0, n);
        k_mixq8<16, 1><<<1024, 256, 0, stream>>>(w_out, WoutC8, sOut, P, 4, 0, 1048576);
        k_mixq8<4, 0><<<4096, 256, 0, stream>>>(w1, W1m8, s1, P, 8, 1, 4194304);
        k_mixq8<16, 0><<<1024, 256, 0, stream>>>(w2, W2m8, s2, P, 12, 2, 4194304);
        k_mixb<<<(4096 + 255) / 256, 256, 0, stream>>>(b1, b1m, P, 1, 4096);
        k_mixb<<<(1024 + 255) / 256, 256, 0, stream>>>(b2, b2m, P, 2, 1024);
        k_mixb<<<(1024 + 255) / 256, 256, 0, stream>>>(b_out, bOm, P, 0, 1024);
        k_si8<<<(2097152 + 255) / 256, 256, 0, stream>>>(src, Si8, P, 2097152);
    }
    // 4 branches: i8 qkv GEMM then flash into attnC columns (+ per-block out-max)
    for (int i = 0; i < 4; ++i) {
        k_gemm_i8<<<dim3(24, 64), 256, 0, stream>>>(
            Si8, WinQ8 + (size_t)i * 3072 * 1024, qkvB, b_in + i * 3072, P, i, MM, 3072, 1024, 1, 8);
        k_fmfma<<<dim3(1024), 256, 0, stream>>>(qkvB, 3072, attnC + i * 1024, 4096,
                                                flashPart + i * 1024);
    }
    k_rmax<<<1, 256, 0, stream>>>(flashPart, 4096, amaxv + 0);
    // quantize attnC -> i8 (qkvB region), fused i8 out-proj with per-col scales
    k_q8<<<(4194304 + 255) / 256, 256, 0, stream>>>(attnC, attnC8, amaxv + 0, 4194304);
    k_gemm_i8s<float, false><<<dim3(8, 64), 256, 0, stream>>>(
        attnC8, WoutC8, outF, bOm, sOut, amaxv + 0, nullptr, MM, 1024, 4096, 4, 2);
    // x = LN(src + src2) -> bf16 + per-block max
    k_ln<<<MM, 256, 0, stream>>>(src, nullptr, outF, g1, be1, nullptr, Xbf, lnPart);
    k_rmax<<<1, 256, 0, stream>>>(lnPart, 8192, amaxv + 1);
    k_q8<<<(1048576 + 255) / 256, 256, 0, stream>>>(Xbf, Xi8, amaxv + 1, 1048576);
    // h = gelu(x @ W1m^T + b1m) -> bf16 (overlay attnC) + per-block max
    k_gemm_i8s<unsigned short, true><<<dim3(32, 64), 256, 0, stream>>>(
        Xi8, W1m8, h, b1m, s1, amaxv + 1, hPart, MM, 4096, 1024, 1, 8);
    k_rmax<<<1, 256, 0, stream>>>(hPart, 2048, amaxv + 2);
    k_q8<<<(4194304 + 255) / 256, 256, 0, stream>>>(h, h8, amaxv + 2, 4194304);
    // y = h8 @ W2m8^T + b2m (overwrites d_out)
    k_gemm_i8s<float, false><<<dim3(8, 64), 256, 0, stream>>>(
        h8, W2m8, outF, b2m, s2, amaxv + 2, nullptr, MM, 1024, 4096, 4, 2);
    // out = LN(x + y)
    k_ln<<<MM, 256, 0, stream>>>(nullptr, Xbf, outF, g2, be2, outF, nullptr, nullptr);
}